// Round 1
// baseline (287.759 us; speedup 1.0000x reference)
//
#include <hip/hip_runtime.h>

// DSR loss: R_t = sum_i w[t,i]*x[t,i];  A_t = c*A_{t-1} + eta*R_t (c=0.99),
// B_t likewise with R^2;  D_t from (A_prev,B_prev);  out = -sum(D)/B.
// Parallel scan over the linear recurrence; fp64 internal math; deterministic
// reduction (per-block sums, no atomics).

#define D_ETA 0.01
#define D_C   (1.0 - D_ETA)
#define D_EPS 1e-8

constexpr int BLOCK = 256;
constexpr int CHUNK = 2048;          // rows per block
constexpr int LPT   = CHUNK / BLOCK; // 8 rows per thread
// padded LDS index: +1 float per 8 to break stride-8 bank conflicts
__device__ __forceinline__ int pidx(int i) { return i + (i >> 3); }
constexpr int RS_SIZE = CHUNK + CHUNK / 8;

__device__ __forceinline__ double row_R(const float* __restrict__ w,
                                        const float* __restrict__ x,
                                        long long row) {
    const float4* w4 = (const float4*)(w + row * 16);
    const float4* x4 = (const float4*)(x + row * 16);
    double r = 0.0;
#pragma unroll
    for (int q = 0; q < 4; ++q) {
        float4 a = w4[q];
        float4 b = x4[q];
        r += (double)a.x * (double)b.x;
        r += (double)a.y * (double)b.y;
        r += (double)a.z * (double)b.z;
        r += (double)a.w * (double)b.w;
    }
    return r;
}

// Hillis-Steele inclusive scan over 256 affine transforms (m, sA, sB).
// combine(prev, cur): x -> m_cur*(m_prev*x + s_prev) + s_cur
__device__ __forceinline__ void block_scan(double& m, double& sA, double& sB,
                                           double* mS, double* aS, double* bS) {
    int tid = threadIdx.x;
    mS[tid] = m; aS[tid] = sA; bS[tid] = sB;
    __syncthreads();
#pragma unroll
    for (int off = 1; off < BLOCK; off <<= 1) {
        double pm = 1.0, pa = 0.0, pb = 0.0;
        if (tid >= off) { pm = mS[tid - off]; pa = aS[tid - off]; pb = bS[tid - off]; }
        __syncthreads();
        if (tid >= off) {
            sA = m * pa + sA;
            sB = m * pb + sB;
            m  = pm * m;
        }
        mS[tid] = m; aS[tid] = sA; bS[tid] = sB;
        __syncthreads();
    }
}

__global__ __launch_bounds__(BLOCK) void k1_partials(
    const float* __restrict__ w, const float* __restrict__ x, int nrows,
    float* __restrict__ Rws,
    double* __restrict__ blkM, double* __restrict__ blkA, double* __restrict__ blkB)
{
    __shared__ float Rs[RS_SIZE];
    __shared__ double mS[BLOCK], aS[BLOCK], bS[BLOCK];
    int tid = threadIdx.x;
    long long base = (long long)blockIdx.x * CHUNK;

#pragma unroll
    for (int j = 0; j < LPT; ++j) {
        int idx = j * BLOCK + tid;
        long long row = base + idx;
        float rv = 0.f;
        if (row < nrows) {
            rv = (float)row_R(w, x, row);
            if (Rws) Rws[row] = rv;
        }
        Rs[pidx(idx)] = rv;
    }
    __syncthreads();

    int start = tid * LPT;
    long long grow = base + start;
    long long rem = (long long)nrows - grow;
    int len = rem >= LPT ? LPT : (rem > 0 ? (int)rem : 0);

    double m = 1.0, sA = 0.0, sB = 0.0;
    for (int k = 0; k < len; ++k) {
        double r = (double)Rs[pidx(start + k)];
        sA = D_C * sA + D_ETA * r;
        sB = D_C * sB + D_ETA * (r * r);
        m *= D_C;
    }
    block_scan(m, sA, sB, mS, aS, bS);
    if (tid == BLOCK - 1) {
        blkM[blockIdx.x] = m;
        blkA[blockIdx.x] = sA;
        blkB[blockIdx.x] = sB;
    }
}

__global__ __launch_bounds__(BLOCK) void k2_scan(
    int nb,
    const double* __restrict__ blkM, const double* __restrict__ blkA,
    const double* __restrict__ blkB,
    double* __restrict__ A0, double* __restrict__ B0)
{
    __shared__ double mS[BLOCK], aS[BLOCK], bS[BLOCK];
    int tid = threadIdx.x;
    int K = (nb + BLOCK - 1) / BLOCK;
    int g0 = tid * K;
    int g1 = g0 + K; if (g1 > nb) g1 = nb;

    double m = 1.0, sA = 0.0, sB = 0.0;
    for (int g = g0; g < g1; ++g) {
        double mg = blkM[g], ag = blkA[g], bg = blkB[g];
        sA = mg * sA + ag;
        sB = mg * sB + bg;
        m *= mg;
    }
    block_scan(m, sA, sB, mS, aS, bS);

    double em = 1.0, ea = 0.0, eb = 0.0;
    if (tid > 0) { em = mS[tid - 1]; ea = aS[tid - 1]; eb = bS[tid - 1]; }
    double A = ea;                 // em*0 + ea
    double B = em * D_EPS + eb;
    for (int g = g0; g < g1; ++g) {
        A0[g] = A; B0[g] = B;
        double mg = blkM[g], ag = blkA[g], bg = blkB[g];
        A = mg * A + ag;
        B = mg * B + bg;
    }
}

__global__ __launch_bounds__(BLOCK) void k3_dsum(
    const float* __restrict__ w, const float* __restrict__ x, int nrows,
    const float* __restrict__ Rws,
    const double* __restrict__ A0, const double* __restrict__ B0,
    double* __restrict__ bsum)
{
    __shared__ float Rs[RS_SIZE];
    __shared__ double mS[BLOCK], aS[BLOCK], bS[BLOCK];
    __shared__ double wsum[BLOCK / 64];
    int tid = threadIdx.x;
    long long base = (long long)blockIdx.x * CHUNK;

#pragma unroll
    for (int j = 0; j < LPT; ++j) {
        int idx = j * BLOCK + tid;
        long long row = base + idx;
        float rv = 0.f;
        if (row < nrows) {
            if (Rws) rv = Rws[row];
            else     rv = (float)row_R(w, x, row);
        }
        Rs[pidx(idx)] = rv;
    }
    __syncthreads();

    int start = tid * LPT;
    long long grow = base + start;
    long long rem = (long long)nrows - grow;
    int len = rem >= LPT ? LPT : (rem > 0 ? (int)rem : 0);

    double m = 1.0, sA = 0.0, sB = 0.0;
    for (int k = 0; k < len; ++k) {
        double r = (double)Rs[pidx(start + k)];
        sA = D_C * sA + D_ETA * r;
        sB = D_C * sB + D_ETA * (r * r);
        m *= D_C;
    }
    block_scan(m, sA, sB, mS, aS, bS);

    double em = 1.0, ea = 0.0, eb = 0.0;
    if (tid > 0) { em = mS[tid - 1]; ea = aS[tid - 1]; eb = bS[tid - 1]; }
    double A = em * A0[blockIdx.x] + ea;
    double B = em * B0[blockIdx.x] + eb;

    double dsum = 0.0;
    for (int k = 0; k < len; ++k) {
        double r = (double)Rs[pidx(start + k)];
        double dA = D_ETA * (r - A);
        double dB = D_ETA * (r * r - B);
        double var = B - A * A;
        if (var < D_EPS) var = D_EPS;
        double denom = var * sqrt(var);
        dsum += (B * dA - 0.5 * A * dB) / denom;
        A += dA;
        B += dB;
    }

    // deterministic block reduction
#pragma unroll
    for (int off = 32; off > 0; off >>= 1) dsum += __shfl_down(dsum, off, 64);
    if ((tid & 63) == 0) wsum[tid >> 6] = dsum;
    __syncthreads();
    if (tid == 0) {
        double s = wsum[0] + wsum[1] + wsum[2] + wsum[3];
        bsum[blockIdx.x] = s;
    }
}

__global__ __launch_bounds__(BLOCK) void k4_final(
    const double* __restrict__ bsum, int nb, int nrows, float* __restrict__ out)
{
    __shared__ double sh[BLOCK / 64];
    int tid = threadIdx.x;
    double s = 0.0;
    for (int i = tid; i < nb; i += BLOCK) s += bsum[i];
#pragma unroll
    for (int off = 32; off > 0; off >>= 1) s += __shfl_down(s, off, 64);
    if ((tid & 63) == 0) sh[tid >> 6] = s;
    __syncthreads();
    if (tid == 0) {
        double t = sh[0] + sh[1] + sh[2] + sh[3];
        out[0] = (float)(-t / (double)nrows);
    }
}

extern "C" void kernel_launch(void* const* d_in, const int* in_sizes, int n_in,
                              void* d_out, int out_size, void* d_ws, size_t ws_size,
                              hipStream_t stream)
{
    const float* w = (const float*)d_in[0];
    const float* x = (const float*)d_in[1];
    int nrows = in_sizes[0] / 16;
    int nb = (nrows + CHUNK - 1) / CHUNK;

    char* ws = (char*)d_ws;
    // layout: [blkM | blkA | blkB | A0 | B0 | bsum] doubles, then R floats
    double* blkM = (double*)(ws + 64);
    double* blkA = blkM + nb;
    double* blkB = blkA + nb;
    double* A0   = blkB + nb;
    double* B0   = A0 + nb;
    double* bsum = B0 + nb;
    size_t off = 64 + (size_t)6 * nb * sizeof(double);
    off = (off + 255) & ~(size_t)255;
    float* Rws = nullptr;
    if (ws_size >= off + (size_t)nrows * sizeof(float))
        Rws = (float*)(ws + off);

    k1_partials<<<nb, BLOCK, 0, stream>>>(w, x, nrows, Rws, blkM, blkA, blkB);
    k2_scan<<<1, BLOCK, 0, stream>>>(nb, blkM, blkA, blkB, A0, B0);
    k3_dsum<<<nb, BLOCK, 0, stream>>>(w, x, nrows, Rws, A0, B0, bsum);
    k4_final<<<1, BLOCK, 0, stream>>>(bsum, nb, nrows, (float*)d_out);
}

// Round 2
// 285.723 us; speedup vs baseline: 1.0071x; 1.0071x over previous
//
#include <hip/hip_runtime.h>

// DSR loss: R_t = sum_i w[t,i]*x[t,i];  A_t = c*A_{t-1} + eta*R_t (c=0.99),
// B_t likewise with R^2;  D_t from (A_prev,B_prev);  out = -sum(D)/B.
//
// R2 structure: K1 = pure streaming dot (unit-stride coalesced, fp64 dot ->
// fp32 R, proven bit-exact vs np ref in R1). K2/K3/K4/K5 do the parallel
// linear-recurrence scan + replay touching only R (8 MB, cache-resident).

#define D_ETA 0.01
#define D_C   (1.0 - D_ETA)
#define D_EPS 1e-8

constexpr int BLOCK = 256;
constexpr int K1_ROWS = 256;         // rows per K1 block (4 iters x 64 rows)
constexpr int CHUNK = 2048;          // rows per scan block
constexpr int LPT   = CHUNK / BLOCK; // 8 rows per thread

// fallback (ws too small): fp64 dot for one row
__device__ __forceinline__ float row_R(const float* __restrict__ w,
                                       const float* __restrict__ x,
                                       long long row) {
    const float4* w4 = (const float4*)(w + row * 16);
    const float4* x4 = (const float4*)(x + row * 16);
    double r = 0.0;
#pragma unroll
    for (int q = 0; q < 4; ++q) {
        float4 a = w4[q];
        float4 b = x4[q];
        r += (double)a.x * (double)b.x;
        r += (double)a.y * (double)b.y;
        r += (double)a.z * (double)b.z;
        r += (double)a.w * (double)b.w;
    }
    return (float)r;
}

// ---------------- K1: streaming dot products ----------------
// 4 consecutive lanes own one row; each lane loads one contiguous float4.
// Per wave-instruction: 64 lanes x 16 B contiguous = 1 KB (coalescing sweet
// spot). Quarter-dot in fp64 (products of fp32 are exact in fp64), cross-lane
// reduce over the 4 lanes, lane 0-of-4 stores fp32 R.
__global__ __launch_bounds__(BLOCK) void k1_dots(
    const float* __restrict__ w, const float* __restrict__ x, int nrows,
    float* __restrict__ R)
{
    int tid = threadIdx.x;
    int q    = tid & 3;   // which float4 within the row
    int rsub = tid >> 2;  // row within group of 64
    long long base = (long long)blockIdx.x * K1_ROWS;
    const float4* w4 = (const float4*)w;
    const float4* x4 = (const float4*)x;
#pragma unroll
    for (int it = 0; it < K1_ROWS / 64; ++it) {
        long long row = base + (long long)it * 64 + rsub;
        if (row < nrows) {
            long long f = row * 4 + q;
            float4 a = w4[f];
            float4 b = x4[f];
            double p = (double)a.x * (double)b.x
                     + (double)a.y * (double)b.y
                     + (double)a.z * (double)b.z
                     + (double)a.w * (double)b.w;
            p += __shfl_xor(p, 1, 64);
            p += __shfl_xor(p, 2, 64);
            if (q == 0) R[row] = (float)p;
        }
    }
}

// Hillis-Steele inclusive scan over 256 affine transforms (m, sA, sB).
__device__ __forceinline__ void block_scan(double& m, double& sA, double& sB,
                                           double* mS, double* aS, double* bS) {
    int tid = threadIdx.x;
    mS[tid] = m; aS[tid] = sA; bS[tid] = sB;
    __syncthreads();
#pragma unroll
    for (int off = 1; off < BLOCK; off <<= 1) {
        double pm = 1.0, pa = 0.0, pb = 0.0;
        if (tid >= off) { pm = mS[tid - off]; pa = aS[tid - off]; pb = bS[tid - off]; }
        __syncthreads();
        if (tid >= off) {
            sA = m * pa + sA;
            sB = m * pb + sB;
            m  = pm * m;
        }
        mS[tid] = m; aS[tid] = sA; bS[tid] = sB;
        __syncthreads();
    }
}

// load this thread's LPT=8 R values (fast float4 path when fully in-range)
__device__ __forceinline__ int load_seg(const float* __restrict__ Rws,
                                        const float* __restrict__ w,
                                        const float* __restrict__ x,
                                        long long g0, int nrows, float* rv) {
    long long rem = (long long)nrows - g0;
    int len = rem >= LPT ? LPT : (rem > 0 ? (int)rem : 0);
    if (Rws) {
        if (len == LPT) {
            const float4* Rp = (const float4*)(Rws + g0);
            float4 u = Rp[0], v = Rp[1];
            rv[0]=u.x; rv[1]=u.y; rv[2]=u.z; rv[3]=u.w;
            rv[4]=v.x; rv[5]=v.y; rv[6]=v.z; rv[7]=v.w;
        } else {
            for (int k = 0; k < len; ++k) rv[k] = Rws[g0 + k];
        }
    } else {
        for (int k = 0; k < len; ++k) rv[k] = row_R(w, x, g0 + k);
    }
    return len;
}

// ---------------- K2: per-chunk affine aggregates ----------------
__global__ __launch_bounds__(BLOCK) void k2_partials(
    const float* __restrict__ Rws,
    const float* __restrict__ w, const float* __restrict__ x, int nrows,
    double* __restrict__ blkM, double* __restrict__ blkA, double* __restrict__ blkB)
{
    __shared__ double mS[BLOCK], aS[BLOCK], bS[BLOCK];
    int tid = threadIdx.x;
    long long g0 = (long long)blockIdx.x * CHUNK + (long long)tid * LPT;
    float rv[LPT];
    int len = load_seg(Rws, w, x, g0, nrows, rv);

    double m = 1.0, sA = 0.0, sB = 0.0;
    for (int k = 0; k < len; ++k) {
        double r = (double)rv[k];
        sA = D_C * sA + D_ETA * r;
        sB = D_C * sB + D_ETA * (r * r);
        m *= D_C;
    }
    block_scan(m, sA, sB, mS, aS, bS);
    if (tid == BLOCK - 1) {
        blkM[blockIdx.x] = m;
        blkA[blockIdx.x] = sA;
        blkB[blockIdx.x] = sB;
    }
}

// ---------------- K3: scan of chunk aggregates (1 block) ----------------
__global__ __launch_bounds__(BLOCK) void k3_scan(
    int nb,
    const double* __restrict__ blkM, const double* __restrict__ blkA,
    const double* __restrict__ blkB,
    double* __restrict__ A0, double* __restrict__ B0)
{
    __shared__ double mS[BLOCK], aS[BLOCK], bS[BLOCK];
    int tid = threadIdx.x;
    int K = (nb + BLOCK - 1) / BLOCK;
    int g0 = tid * K;
    int g1 = g0 + K; if (g1 > nb) g1 = nb;

    double m = 1.0, sA = 0.0, sB = 0.0;
    for (int g = g0; g < g1; ++g) {
        double mg = blkM[g], ag = blkA[g], bg = blkB[g];
        sA = mg * sA + ag;
        sB = mg * sB + bg;
        m *= mg;
    }
    block_scan(m, sA, sB, mS, aS, bS);

    double em = 1.0, ea = 0.0, eb = 0.0;
    if (tid > 0) { em = mS[tid - 1]; ea = aS[tid - 1]; eb = bS[tid - 1]; }
    double A = ea;                 // em*0 + ea
    double B = em * D_EPS + eb;
    for (int g = g0; g < g1; ++g) {
        A0[g] = A; B0[g] = B;
        double mg = blkM[g], ag = blkA[g], bg = blkB[g];
        A = mg * A + ag;
        B = mg * B + bg;
    }
}

// ---------------- K4: replay + D sum ----------------
__global__ __launch_bounds__(BLOCK) void k4_dsum(
    const float* __restrict__ Rws,
    const float* __restrict__ w, const float* __restrict__ x, int nrows,
    const double* __restrict__ A0, const double* __restrict__ B0,
    double* __restrict__ bsum)
{
    __shared__ double mS[BLOCK], aS[BLOCK], bS[BLOCK];
    __shared__ double wsum[BLOCK / 64];
    int tid = threadIdx.x;
    long long g0 = (long long)blockIdx.x * CHUNK + (long long)tid * LPT;
    float rv[LPT];
    int len = load_seg(Rws, w, x, g0, nrows, rv);

    double m = 1.0, sA = 0.0, sB = 0.0;
    for (int k = 0; k < len; ++k) {
        double r = (double)rv[k];
        sA = D_C * sA + D_ETA * r;
        sB = D_C * sB + D_ETA * (r * r);
        m *= D_C;
    }
    block_scan(m, sA, sB, mS, aS, bS);

    double em = 1.0, ea = 0.0, eb = 0.0;
    if (tid > 0) { em = mS[tid - 1]; ea = aS[tid - 1]; eb = bS[tid - 1]; }
    double A = em * A0[blockIdx.x] + ea;
    double B = em * B0[blockIdx.x] + eb;

    double dsum = 0.0;
    for (int k = 0; k < len; ++k) {
        double r = (double)rv[k];
        double dA = D_ETA * (r - A);
        double dB = D_ETA * (r * r - B);
        double var = B - A * A;
        if (var < D_EPS) var = D_EPS;
        double denom = var * sqrt(var);
        dsum += (B * dA - 0.5 * A * dB) / denom;
        A += dA;
        B += dB;
    }

#pragma unroll
    for (int off = 32; off > 0; off >>= 1) dsum += __shfl_down(dsum, off, 64);
    if ((tid & 63) == 0) wsum[tid >> 6] = dsum;
    __syncthreads();
    if (tid == 0) bsum[blockIdx.x] = wsum[0] + wsum[1] + wsum[2] + wsum[3];
}

// ---------------- K5: final reduction ----------------
__global__ __launch_bounds__(BLOCK) void k5_final(
    const double* __restrict__ bsum, int nb, int nrows, float* __restrict__ out)
{
    __shared__ double sh[BLOCK / 64];
    int tid = threadIdx.x;
    double s = 0.0;
    for (int i = tid; i < nb; i += BLOCK) s += bsum[i];
#pragma unroll
    for (int off = 32; off > 0; off >>= 1) s += __shfl_down(s, off, 64);
    if ((tid & 63) == 0) sh[tid >> 6] = s;
    __syncthreads();
    if (tid == 0) out[0] = (float)(-(sh[0] + sh[1] + sh[2] + sh[3]) / (double)nrows);
}

extern "C" void kernel_launch(void* const* d_in, const int* in_sizes, int n_in,
                              void* d_out, int out_size, void* d_ws, size_t ws_size,
                              hipStream_t stream)
{
    const float* w = (const float*)d_in[0];
    const float* x = (const float*)d_in[1];
    int nrows = in_sizes[0] / 16;
    int nb  = (nrows + CHUNK - 1) / CHUNK;
    int nb1 = (nrows + K1_ROWS - 1) / K1_ROWS;

    char* ws = (char*)d_ws;
    double* blkM = (double*)(ws + 64);
    double* blkA = blkM + nb;
    double* blkB = blkA + nb;
    double* A0   = blkB + nb;
    double* B0   = A0 + nb;
    double* bsum = B0 + nb;
    size_t off = 64 + (size_t)6 * nb * sizeof(double);
    off = (off + 255) & ~(size_t)255;
    float* Rws = nullptr;
    if (ws_size >= off + (size_t)nrows * sizeof(float))
        Rws = (float*)(ws + off);

    if (Rws)
        k1_dots<<<nb1, BLOCK, 0, stream>>>(w, x, nrows, Rws);
    k2_partials<<<nb, BLOCK, 0, stream>>>(Rws, w, x, nrows, blkM, blkA, blkB);
    k3_scan<<<1, BLOCK, 0, stream>>>(nb, blkM, blkA, blkB, A0, B0);
    k4_dsum<<<nb, BLOCK, 0, stream>>>(Rws, w, x, nrows, A0, B0, bsum);
    k5_final<<<1, BLOCK, 0, stream>>>(bsum, nb, nrows, (float*)d_out);
}